// Round 2
// baseline (704.475 us; speedup 1.0000x reference)
//
#include <hip/hip_runtime.h>
#include <math.h>

#ifndef M_PI
#define M_PI 3.14159265358979323846
#endif

#define BB 1024
#define SIZE 512
#define NF 128
#define WIDTH 32
#define TOTAL (SIZE*NF)

// ---------------------------------------------------------------------------
// Kernel 1: per-sample FNO frontend -> pooled[b][32] and R[b][128]
// ---------------------------------------------------------------------------
__global__ __launch_bounds__(256) void fno_pooled_kernel(
    const int*   __restrict__ n,
    const float* __restrict__ lift_W,
    const float* __restrict__ lift_b,
    const float* __restrict__ spec_Wr,
    const float* __restrict__ spec_Wi,
    const float* __restrict__ pw_W,
    const float* __restrict__ pw_b,
    float* __restrict__ pooled_g,
    int*   __restrict__ R_g)
{
    __shared__ float nf[SIZE];
    __shared__ float c32[32], s32[32];
    __shared__ float Gre[16], Gim[16];
    __shared__ float wsum[4][32];
    __shared__ float Ar[WIDTH][16], Ai[WIDTH][16];
    __shared__ float lowr[WIDTH][16], lowi[WIDTH][16];
    __shared__ float pwl[WIDTH], cb0[WIDTH];
    __shared__ float Br[WIDTH], Bi[WIDTH];
    __shared__ int   Rl[NF];

    const int b = blockIdx.x;
    const int t = threadIdx.x;
    const int lane = t & 63;
    const int wave = t >> 6;

    if (t < 32) {
        float ang = (float)t * (2.0f * (float)M_PI / 32.0f);
        c32[t] = cosf(ang);
        s32[t] = sinf(ang);
    }
    for (int p = t; p < SIZE; p += 256) nf[p] = (float)n[b*SIZE + p];
    if (t < NF) Rl[t] = 0;
    __syncthreads();

    // R = first 128 nonzero indices (ballot scan, wave 0)
    if (wave == 0) {
        int base = 0;
        for (int c = 0; c < 8; ++c) {
            int p = c*64 + lane;
            bool occ = (nf[p] != 0.0f);
            unsigned long long mask = __ballot(occ);
            int prefix = __popcll(mask & ((1ull << lane) - 1ull));
            if (occ) {
                int idx = base + prefix;
                if (idx < NF) Rl[idx] = p;
            }
            base += __popcll(mask);
        }
    }

    // G[kx,ky] = sum_p nf[p] * exp(-2pi i (kx*x/32 + ky*y/16)),  p=(x,y), x=p>>4, y=p&15
    float gre[16], gim[16];
    #pragma unroll
    for (int m = 0; m < 16; ++m) { gre[m] = 0.f; gim[m] = 0.f; }
    for (int p = t; p < SIZE; p += 256) {
        float v = nf[p];
        int x = p >> 4, y = p & 15;
        #pragma unroll
        for (int kx = 0; kx < 4; ++kx) {
            #pragma unroll
            for (int ky = 0; ky < 4; ++ky) {
                int idx = (kx*x + 2*ky*y) & 31;
                gre[kx*4+ky] += v * c32[idx];
                gim[kx*4+ky] -= v * s32[idx];
            }
        }
    }
    #pragma unroll
    for (int m = 0; m < 16; ++m) {
        for (int off = 32; off > 0; off >>= 1) {
            gre[m] += __shfl_xor(gre[m], off, 64);
            gim[m] += __shfl_xor(gim[m], off, 64);
        }
    }
    if (lane == 0) {
        #pragma unroll
        for (int m = 0; m < 16; ++m) { wsum[wave][m] = gre[m]; wsum[wave][16+m] = gim[m]; }
    }
    __syncthreads();
    if (t < 32) {
        float s = wsum[0][t] + wsum[1][t] + wsum[2][t] + wsum[3][t];
        if (t < 16) Gre[t] = s; else Gim[t-16] = s;
    }

    // A_oc[o,m] = sum_i lift_W[i] * Wc[i,o,m]   (sample-independent, cheap)
    for (int idx = t; idx < 512; idx += 256) {
        int o = idx >> 4, m = idx & 15;
        float ar = 0.f, ai = 0.f;
        for (int i = 0; i < WIDTH; ++i) {
            float lw = lift_W[i];
            ar += lw * spec_Wr[i*512 + o*16 + m];
            ai += lw * spec_Wi[i*512 + o*16 + m];
        }
        Ar[o][m] = ar; Ai[o][m] = ai;
    }
    // DC bias term + pointwise-path constants
    if (t < 32) {
        float br = 0.f, bi = 0.f, pl = 0.f, cb = 0.f;
        for (int i = 0; i < WIDTH; ++i) {
            float lb = lift_b[i];
            br += lb * spec_Wr[i*512 + t*16 + 0];
            bi += lb * spec_Wi[i*512 + t*16 + 0];
            pl += lift_W[i] * pw_W[i*WIDTH + t];
            cb += lb * pw_W[i*WIDTH + t];
        }
        Br[t] = br; Bi[t] = bi;
        pwl[t] = pl;
        cb0[t] = cb + pw_b[t];
    }
    __syncthreads();

    // low[o,kx,ky] = G * A_oc  (+ H*W * bias term at DC)
    for (int idx = t; idx < 512; idx += 256) {
        int o = idx >> 4, m = idx & 15;
        float gr = Gre[m], gi = Gim[m];
        float ar = Ar[o][m], ai = Ai[o][m];
        float lr = gr*ar - gi*ai;
        float li = gr*ai + gi*ar;
        if (m == 0) { lr += 512.f * Br[o]; li += 512.f * Bi[o]; }
        lowr[o][m] = lr; lowi[o][m] = li;
    }
    __syncthreads();

    // per (o,x): T_ky(x) = (1/32) sum_kx low * e^{+2pi i kx x/32}; then y loop, tanh, mean
    const int o  = t >> 3;
    const int xg = t & 7;
    const float plo = pwl[o], cbo = cb0[o];
    float acc = 0.f;
    const float inv32 = 1.0f/32.0f, inv16 = 1.0f/16.0f;
    for (int xi = 0; xi < 4; ++xi) {
        int x = xg*4 + xi;
        float Tre[4], Tim[4];
        #pragma unroll
        for (int ky = 0; ky < 4; ++ky) { Tre[ky] = 0.f; Tim[ky] = 0.f; }
        #pragma unroll
        for (int kx = 0; kx < 4; ++kx) {
            int idx = (kx*x) & 31;
            float c = c32[idx], s = s32[idx];
            #pragma unroll
            for (int ky = 0; ky < 4; ++ky) {
                float lr = lowr[o][kx*4+ky], li = lowi[o][kx*4+ky];
                Tre[ky] += lr*c - li*s;
                Tim[ky] += lr*s + li*c;
            }
        }
        #pragma unroll
        for (int ky = 0; ky < 4; ++ky) { Tre[ky] *= inv32; Tim[ky] *= inv32; }
        for (int y = 0; y < 16; ++y) {
            float hsv = Tre[0];
            #pragma unroll
            for (int ky = 1; ky < 4; ++ky) {
                int idx = (2*ky*y) & 31;
                hsv += 2.f*(Tre[ky]*c32[idx] - Tim[ky]*s32[idx]);
            }
            hsv *= inv16;
            float z = hsv + nf[x*16 + y]*plo + cbo;
            acc += tanhf(z);
        }
    }
    acc += __shfl_down(acc, 4, 8);
    acc += __shfl_down(acc, 2, 8);
    acc += __shfl_down(acc, 1, 8);
    if ((t & 7) == 0) pooled_g[b*WIDTH + o] = acc * (1.0f/512.0f);

    if (t < NF) R_g[b*NF + t] = Rl[t];
}

// ---------------------------------------------------------------------------
// Kernel 2: per-sample build A (gathered rows) + LU w/ partial pivoting -> out
// Output layout: PLANAR — out[b] = logabs, out[BB + b] = imag (0 or pi)
// ---------------------------------------------------------------------------
__global__ __launch_bounds__(256) void build_lu_kernel(
    const float* __restrict__ M_base,
    const float* __restrict__ proj_W,
    const float* __restrict__ proj_b,
    const float* __restrict__ pooled_g,
    const int*   __restrict__ R_g,
    float* __restrict__ out)
{
    __shared__ float A[NF][NF + 1];   // +1 pad: column access conflict-free
    __shared__ float lcol[NF];
    __shared__ float pooled_s[WIDTH];
    __shared__ int   Rl[NF];
    __shared__ int   piv;
    __shared__ int   nswap;

    const int b = blockIdx.x;
    const int t = threadIdx.x;

    if (t < WIDTH) pooled_s[t] = pooled_g[b*WIDTH + t];
    if (t < NF)    Rl[t] = R_g[b*NF + t];
    if (t == 0)    nswap = 0;
    __syncthreads();

    const int j    = t & 127;
    const int half = t >> 7;

    // A[i][j] = M_base[r,j] + proj_b[r*128+j] + sum_o pooled[o]*proj_W[o, r*128+j]
    for (int i = half; i < NF; i += 2) {
        int r = Rl[i];
        int base = r*NF + j;
        float val = M_base[base] + proj_b[base];
        #pragma unroll 8
        for (int o = 0; o < WIDTH; ++o)
            val += pooled_s[o] * proj_W[o*TOTAL + base];
        A[i][j] = val;
    }
    __syncthreads();

    for (int k = 0; k < NF; ++k) {
        // pivot search (wave 0 only)
        if (t < 64) {
            float bv = -1.f; int bidx = k;
            for (int i = k + t; i < NF; i += 64) {
                float v = fabsf(A[i][k]);
                if (v > bv) { bv = v; bidx = i; }
            }
            for (int off = 32; off > 0; off >>= 1) {
                float ov = __shfl_xor(bv, off, 64);
                int   oi = __shfl_xor(bidx, off, 64);
                if (ov > bv || (ov == bv && oi < bidx)) { bv = ov; bidx = oi; }
            }
            if (t == 0) { piv = bidx; if (bidx != k) nswap++; }
        }
        __syncthreads();
        int p = piv;
        if (p != k && t < NF) {
            float tmp = A[k][t]; A[k][t] = A[p][t]; A[p][t] = tmp;
        }
        __syncthreads();
        float pv = A[k][k];
        if (t > k && t < NF) lcol[t] = A[t][k] / pv;
        __syncthreads();
        if (j > k) {
            float akj = A[k][j];
            int i0 = k + 1;
            if ((i0 & 1) != half) i0++;
            for (int i = i0; i < NF; i += 2)
                A[i][j] -= lcol[i] * akj;
        }
        __syncthreads();
    }

    // logabs = sum log|U_kk|; sign from diag negatives ^ swap parity
    if (t < 64) {
        float lsum = 0.f; int neg = 0;
        for (int k2 = t; k2 < NF; k2 += 64) {
            float d = A[k2][k2];
            lsum += logf(fabsf(d));
            if (d < 0.f) neg ^= 1;
        }
        for (int off = 32; off > 0; off >>= 1) {
            lsum += __shfl_xor(lsum, off, 64);
            neg  ^= __shfl_xor(neg,  off, 64);
        }
        if (t == 0) {
            int parity = (neg ^ (nswap & 1)) & 1;
            out[b]      = lsum;                          // planar: real part
            out[BB + b] = parity ? (float)M_PI : 0.0f;   // planar: imag part
        }
    }
}

// ---------------------------------------------------------------------------
extern "C" void kernel_launch(void* const* d_in, const int* in_sizes, int n_in,
                              void* d_out, int out_size, void* d_ws, size_t ws_size,
                              hipStream_t stream) {
    const int*   n       = (const int*)  d_in[0];
    const float* M_base  = (const float*)d_in[1];
    const float* lift_W  = (const float*)d_in[2];
    const float* lift_b  = (const float*)d_in[3];
    const float* spec_Wr = (const float*)d_in[4];
    const float* spec_Wi = (const float*)d_in[5];
    const float* pw_W    = (const float*)d_in[6];
    const float* pw_b    = (const float*)d_in[7];
    const float* proj_W  = (const float*)d_in[8];
    const float* proj_b  = (const float*)d_in[9];

    float* pooled = (float*)d_ws;
    int*   R      = (int*)((char*)d_ws + (size_t)BB*WIDTH*sizeof(float));

    fno_pooled_kernel<<<BB, 256, 0, stream>>>(n, lift_W, lift_b, spec_Wr, spec_Wi,
                                              pw_W, pw_b, pooled, R);
    build_lu_kernel<<<BB, 256, 0, stream>>>(M_base, proj_W, proj_b, pooled, R,
                                            (float*)d_out);
}

// Round 3
// 557.279 us; speedup vs baseline: 1.2641x; 1.2641x over previous
//
#include <hip/hip_runtime.h>
#include <math.h>

#ifndef M_PI
#define M_PI 3.14159265358979323846
#endif

#define BB 1024
#define SIZE 512
#define NF 128
#define WIDTH 32
#define TOTAL (SIZE*NF)

// ---------------------------------------------------------------------------
// Swizzled LDS matrix layout: element (i,j) lives at float-index
//   i*128 + ((((j>>2) ^ (i&7)) << 2) | (j&3))
// Groups of 4 floats stay contiguous (b128-able); group index XOR'd with i&7
// spreads a column read across 8 bank-groups (full b128 throughput).
// ---------------------------------------------------------------------------
__device__ __forceinline__ int agrp(int i, int G) {  // float-index of group G (16B aligned)
    return i*128 + ((G ^ (i & 7)) << 2);
}
__device__ __forceinline__ int aidx(int i, int j) {
    return i*128 + ((((j >> 2) ^ (i & 7)) << 2) | (j & 3));
}

// ---------------------------------------------------------------------------
// Kernel 1: per-sample FNO frontend -> pooled[b][32] and R[b][128]
// ---------------------------------------------------------------------------
__global__ __launch_bounds__(256) void fno_pooled_kernel(
    const int*   __restrict__ n,
    const float* __restrict__ lift_W,
    const float* __restrict__ lift_b,
    const float* __restrict__ spec_Wr,
    const float* __restrict__ spec_Wi,
    const float* __restrict__ pw_W,
    const float* __restrict__ pw_b,
    float* __restrict__ pooled_g,
    int*   __restrict__ R_g)
{
    __shared__ float nf[SIZE];
    __shared__ float c32[32], s32[32];
    __shared__ float Gre[16], Gim[16];
    __shared__ float wsum[4][32];
    __shared__ float Ar[WIDTH][16], Ai[WIDTH][16];
    __shared__ float lowr[WIDTH][16], lowi[WIDTH][16];
    __shared__ float pwl[WIDTH], cb0[WIDTH];
    __shared__ float Br[WIDTH], Bi[WIDTH];
    __shared__ int   Rl[NF];

    const int b = blockIdx.x;
    const int t = threadIdx.x;
    const int lane = t & 63;
    const int wave = t >> 6;

    if (t < 32) {
        float ang = (float)t * (2.0f * (float)M_PI / 32.0f);
        c32[t] = cosf(ang);
        s32[t] = sinf(ang);
    }
    for (int p = t; p < SIZE; p += 256) nf[p] = (float)n[b*SIZE + p];
    if (t < NF) Rl[t] = 0;
    __syncthreads();

    if (wave == 0) {
        int base = 0;
        for (int c = 0; c < 8; ++c) {
            int p = c*64 + lane;
            bool occ = (nf[p] != 0.0f);
            unsigned long long mask = __ballot(occ);
            int prefix = __popcll(mask & ((1ull << lane) - 1ull));
            if (occ) {
                int idx = base + prefix;
                if (idx < NF) Rl[idx] = p;
            }
            base += __popcll(mask);
        }
    }

    float gre[16], gim[16];
    #pragma unroll
    for (int m = 0; m < 16; ++m) { gre[m] = 0.f; gim[m] = 0.f; }
    for (int p = t; p < SIZE; p += 256) {
        float v = nf[p];
        int x = p >> 4, y = p & 15;
        #pragma unroll
        for (int kx = 0; kx < 4; ++kx) {
            #pragma unroll
            for (int ky = 0; ky < 4; ++ky) {
                int idx = (kx*x + 2*ky*y) & 31;
                gre[kx*4+ky] += v * c32[idx];
                gim[kx*4+ky] -= v * s32[idx];
            }
        }
    }
    #pragma unroll
    for (int m = 0; m < 16; ++m) {
        for (int off = 32; off > 0; off >>= 1) {
            gre[m] += __shfl_xor(gre[m], off, 64);
            gim[m] += __shfl_xor(gim[m], off, 64);
        }
    }
    if (lane == 0) {
        #pragma unroll
        for (int m = 0; m < 16; ++m) { wsum[wave][m] = gre[m]; wsum[wave][16+m] = gim[m]; }
    }
    __syncthreads();
    if (t < 32) {
        float s = wsum[0][t] + wsum[1][t] + wsum[2][t] + wsum[3][t];
        if (t < 16) Gre[t] = s; else Gim[t-16] = s;
    }

    for (int idx = t; idx < 512; idx += 256) {
        int o = idx >> 4, m = idx & 15;
        float ar = 0.f, ai = 0.f;
        for (int i = 0; i < WIDTH; ++i) {
            float lw = lift_W[i];
            ar += lw * spec_Wr[i*512 + o*16 + m];
            ai += lw * spec_Wi[i*512 + o*16 + m];
        }
        Ar[o][m] = ar; Ai[o][m] = ai;
    }
    if (t < 32) {
        float br = 0.f, bi = 0.f, pl = 0.f, cb = 0.f;
        for (int i = 0; i < WIDTH; ++i) {
            float lb = lift_b[i];
            br += lb * spec_Wr[i*512 + t*16 + 0];
            bi += lb * spec_Wi[i*512 + t*16 + 0];
            pl += lift_W[i] * pw_W[i*WIDTH + t];
            cb += lb * pw_W[i*WIDTH + t];
        }
        Br[t] = br; Bi[t] = bi;
        pwl[t] = pl;
        cb0[t] = cb + pw_b[t];
    }
    __syncthreads();

    for (int idx = t; idx < 512; idx += 256) {
        int o = idx >> 4, m = idx & 15;
        float gr = Gre[m], gi = Gim[m];
        float ar = Ar[o][m], ai = Ai[o][m];
        float lr = gr*ar - gi*ai;
        float li = gr*ai + gi*ar;
        if (m == 0) { lr += 512.f * Br[o]; li += 512.f * Bi[o]; }
        lowr[o][m] = lr; lowi[o][m] = li;
    }
    __syncthreads();

    const int o  = t >> 3;
    const int xg = t & 7;
    const float plo = pwl[o], cbo = cb0[o];
    float acc = 0.f;
    const float inv32 = 1.0f/32.0f, inv16 = 1.0f/16.0f;
    for (int xi = 0; xi < 4; ++xi) {
        int x = xg*4 + xi;
        float Tre[4], Tim[4];
        #pragma unroll
        for (int ky = 0; ky < 4; ++ky) { Tre[ky] = 0.f; Tim[ky] = 0.f; }
        #pragma unroll
        for (int kx = 0; kx < 4; ++kx) {
            int idx = (kx*x) & 31;
            float c = c32[idx], s = s32[idx];
            #pragma unroll
            for (int ky = 0; ky < 4; ++ky) {
                float lr = lowr[o][kx*4+ky], li = lowi[o][kx*4+ky];
                Tre[ky] += lr*c - li*s;
                Tim[ky] += lr*s + li*c;
            }
        }
        #pragma unroll
        for (int ky = 0; ky < 4; ++ky) { Tre[ky] *= inv32; Tim[ky] *= inv32; }
        for (int y = 0; y < 16; ++y) {
            float hsv = Tre[0];
            #pragma unroll
            for (int ky = 1; ky < 4; ++ky) {
                int idx = (2*ky*y) & 31;
                hsv += 2.f*(Tre[ky]*c32[idx] - Tim[ky]*s32[idx]);
            }
            hsv *= inv16;
            float z = hsv + nf[x*16 + y]*plo + cbo;
            acc += tanhf(z);
        }
    }
    acc += __shfl_down(acc, 4, 8);
    acc += __shfl_down(acc, 2, 8);
    acc += __shfl_down(acc, 1, 8);
    if ((t & 7) == 0) pooled_g[b*WIDTH + o] = acc * (1.0f/512.0f);

    if (t < NF) R_g[b*NF + t] = Rl[t];
}

// ---------------------------------------------------------------------------
// Kernel 2: build gathered A + rank-4 blocked LU (partial pivoting) -> out
// 512 threads: thread t -> row i = t&127, column-quarter q = t>>7 (8 groups).
// Per 4-col panel: wave 0 does 4 pivot searches entirely in registers
// (l-columns + 4x4 U block replicated via shfl), computes M=L11^{-1},
// composite row coefs, copies pivot rows to Raw; then ONE barrier and all
// threads apply the rank-4 trailing update with float4 LDS ops.
// Output planar: out[b]=logabs, out[BB+b]=0 or pi.
// ---------------------------------------------------------------------------
__global__ __launch_bounds__(512) void build_lu_kernel(
    const float* __restrict__ M_base,
    const float* __restrict__ proj_W,
    const float* __restrict__ proj_b,
    const float* __restrict__ pooled_g,
    const int*   __restrict__ R_g,
    float* __restrict__ out)
{
    __shared__ float A[128*128];       // swizzled
    __shared__ float Raw[4*128];       // pre-panel pivot rows, linear
    __shared__ float coefb[128*5];     // stride-5 pad
    __shared__ float Mb[16];
    __shared__ float pvbuf[128];
    __shared__ int   pivseq[128];
    __shared__ int   pr4[4];
    __shared__ float pooled_s[WIDTH];
    __shared__ int   Rl[NF];

    const int b = blockIdx.x;
    const int t = threadIdx.x;
    const int i = t & 127;
    const int q = t >> 7;

    if (t < WIDTH) pooled_s[t] = pooled_g[b*WIDTH + t];
    if (t < NF)    Rl[t] = R_g[b*NF + t];
    __syncthreads();

    // ---- build: A[i][j] = M_base[r,j] + proj_b[r*128+j] + sum_o pooled[o]*proj_W[o,r*128+j]
    {
        const int r = Rl[i];
        const size_t off0 = (size_t)r*NF + q*32;
        float4 acc[8];
        const float4* mb = (const float4*)(M_base + off0);
        const float4* pb = (const float4*)(proj_b + off0);
        #pragma unroll
        for (int g = 0; g < 8; ++g) {
            float4 a = mb[g], c = pb[g];
            acc[g] = make_float4(a.x+c.x, a.y+c.y, a.z+c.z, a.w+c.w);
        }
        for (int o = 0; o < WIDTH; ++o) {
            const float p = pooled_s[o];
            const float4* w = (const float4*)(proj_W + (size_t)o*TOTAL + off0);
            #pragma unroll
            for (int g = 0; g < 8; ++g) {
                float4 wv = w[g];
                acc[g].x += p*wv.x; acc[g].y += p*wv.y;
                acc[g].z += p*wv.z; acc[g].w += p*wv.w;
            }
        }
        #pragma unroll
        for (int g = 0; g < 8; ++g)
            *((float4*)&A[agrp(i, q*8+g)]) = acc[g];
    }
    __syncthreads();

    bool done_i = false;          // row i already chosen as pivot (all threads)
    bool done0 = false, done1 = false;  // wave0: rows lane, lane+64

    for (int p = 0; p < 32; ++p) {
        const int c = 4*p;

        if (t < 64) {
            const int lane = t;
            float lr0[4], lr1[4];
            float u4[4][4];
            int   prreg[4];

            #pragma unroll
            for (int k = 0; k < 4; ++k) {
                const int cc = c + k;
                float v0 = A[aidx(lane,      cc)];
                float v1 = A[aidx(lane + 64, cc)];
                #pragma unroll
                for (int s = 0; s < 4; ++s) if (s < k) {
                    v0 -= lr0[s] * u4[s][k];
                    v1 -= lr1[s] * u4[s][k];
                }
                float ab0 = done0 ? -1.f : fabsf(v0);
                float ab1 = done1 ? -1.f : fabsf(v1);
                float ab = ab0, val = v0; int idx = lane;
                if (ab1 > ab0) { ab = ab1; val = v1; idx = lane + 64; }
                #pragma unroll
                for (int off = 32; off > 0; off >>= 1) {
                    float oab  = __shfl_xor(ab,  off, 64);
                    float oval = __shfl_xor(val, off, 64);
                    int   oidx = __shfl_xor(idx, off, 64);
                    if (oab > ab || (oab == ab && oidx < idx)) { ab = oab; val = oval; idx = oidx; }
                }
                const int   pk = idx;   // replicated
                const float pv = val;   // replicated
                prreg[k] = pk;
                if (lane == 0) { pivseq[cc] = pk; pvbuf[cc] = pv; }
                lr0[k] = (done0 || lane      == pk) ? 0.f : v0 / pv;
                lr1[k] = (done1 || lane + 64 == pk) ? 0.f : v1 / pv;
                if (lane      == pk) done0 = true;
                if (lane + 64 == pk) done1 = true;
                // fill U row k at panel cols k'>k (replicated in all lanes)
                #pragma unroll
                for (int kp = 0; kp < 4; ++kp) if (kp > k) {
                    float valu = A[aidx(pk, c + kp)];   // broadcast read
                    #pragma unroll
                    for (int s = 0; s < 4; ++s) if (s < k) {
                        float lpks = __shfl((pk < 64) ? lr0[s] : lr1[s], pk & 63, 64);
                        valu -= lpks * u4[s][kp];
                    }
                    u4[k][kp] = valu;
                }
            }

            // L11 strict-lower (Lt[s][sp] = l of row pr[s] at step sp<s), replicated
            float Lt[4][4];
            #pragma unroll
            for (int s = 0; s < 4; ++s) {
                #pragma unroll
                for (int sp = 0; sp < 4; ++sp) if (sp < s)
                    Lt[s][sp] = __shfl((prreg[s] < 64) ? lr0[sp] : lr1[sp], prreg[s] & 63, 64);
            }
            // M = (I + Lt)^{-1}, unit lower, by forward substitution (replicated)
            float m[4][4];
            #pragma unroll
            for (int a_ = 0; a_ < 4; ++a_)
                #pragma unroll
                for (int b_ = 0; b_ < 4; ++b_) m[a_][b_] = (a_ == b_) ? 1.f : 0.f;
            #pragma unroll
            for (int c0 = 0; c0 < 4; ++c0)
                #pragma unroll
                for (int s = 0; s < 4; ++s) if (s > c0) {
                    float accm = 0.f;
                    #pragma unroll
                    for (int sp = 0; sp < 4; ++sp) if (sp >= c0 && sp < s)
                        accm += Lt[s][sp] * m[sp][c0];
                    m[s][c0] = -accm;
                }
            if (lane < 4)  pr4[lane] = prreg[lane];
            if (lane < 16) Mb[lane]  = m[lane >> 2][lane & 3];
            // composite coefs for active rows: coef = -(lrow . M)
            #pragma unroll
            for (int sp = 0; sp < 4; ++sp) {
                float c0v = 0.f, c1v = 0.f;
                #pragma unroll
                for (int s = 0; s < 4; ++s) { c0v += lr0[s]*m[s][sp]; c1v += lr1[s]*m[s][sp]; }
                coefb[lane*5 + sp]      = -c0v;
                coefb[(lane+64)*5 + sp] = -c1v;
            }
            // copy pivot rows (pre-panel values) to Raw (linear layout)
            #pragma unroll
            for (int h = 0; h < 2; ++h) {
                int id = lane + 64*h;
                int s = id >> 5, G = id & 31;
                float4 v = *((const float4*)&A[agrp(prreg[s], G)]);
                *((float4*)&Raw[s*128 + G*4]) = v;
            }
        }
        __syncthreads();

        // rank-4 trailing update (all 512 threads), groups G > p only
        {
            int fp = -1;
            #pragma unroll
            for (int s = 0; s < 4; ++s) if (i == pr4[s]) fp = s;
            if (fp >= 0 || !done_i) {
                float cf[4];
                if (fp >= 0) {
                    #pragma unroll
                    for (int s = 0; s < 4; ++s) cf[s] = Mb[fp*4 + s];   // zeros above diag
                } else {
                    #pragma unroll
                    for (int s = 0; s < 4; ++s) cf[s] = coefb[i*5 + s];
                }
                #pragma unroll
                for (int g = 0; g < 8; ++g) {
                    const int G = q*8 + g;
                    if (G > p) {
                        float4 own;
                        if (fp >= 0) own = make_float4(0.f, 0.f, 0.f, 0.f);
                        else         own = *((const float4*)&A[agrp(i, G)]);
                        #pragma unroll
                        for (int s = 0; s < 4; ++s) {
                            float4 rv = *((const float4*)&Raw[s*128 + G*4]); // broadcast
                            own.x += cf[s]*rv.x; own.y += cf[s]*rv.y;
                            own.z += cf[s]*rv.z; own.w += cf[s]*rv.w;
                        }
                        *((float4*)&A[agrp(i, G)]) = own;
                    }
                }
                if (fp >= 0) done_i = true;
            }
        }
        __syncthreads();
    }

    // ---- logabs + sign ----
    if (t < 64) {
        const int lane = t;
        float d0 = pvbuf[lane], d1 = pvbuf[lane + 64];
        float ls = logf(fabsf(d0)) + logf(fabsf(d1));
        int neg = ((d0 < 0.f) ? 1 : 0) ^ ((d1 < 0.f) ? 1 : 0);
        #pragma unroll
        for (int off = 32; off > 0; off >>= 1) {
            ls  += __shfl_xor(ls,  off, 64);
            neg ^= __shfl_xor(neg, off, 64);
        }
        if (lane == 0) {
            // permutation parity of pivseq via cycle counting
            unsigned long long vis0 = 0ull, vis1 = 0ull;
            int trans = 0;
            for (int k = 0; k < 128; ++k) {
                bool vk = (k < 64) ? ((vis0 >> k) & 1ull) : ((vis1 >> (k - 64)) & 1ull);
                if (!vk) {
                    int j = k, len = 0;
                    while (true) {
                        bool vj = (j < 64) ? ((vis0 >> j) & 1ull) : ((vis1 >> (j - 64)) & 1ull);
                        if (vj) break;
                        if (j < 64) vis0 |= (1ull << j); else vis1 |= (1ull << (j - 64));
                        j = pivseq[j];
                        ++len;
                    }
                    trans += len - 1;
                }
            }
            int parity = (neg ^ (trans & 1)) & 1;
            out[b]      = ls;
            out[BB + b] = parity ? (float)M_PI : 0.0f;
        }
    }
}

// ---------------------------------------------------------------------------
extern "C" void kernel_launch(void* const* d_in, const int* in_sizes, int n_in,
                              void* d_out, int out_size, void* d_ws, size_t ws_size,
                              hipStream_t stream) {
    const int*   n       = (const int*)  d_in[0];
    const float* M_base  = (const float*)d_in[1];
    const float* lift_W  = (const float*)d_in[2];
    const float* lift_b  = (const float*)d_in[3];
    const float* spec_Wr = (const float*)d_in[4];
    const float* spec_Wi = (const float*)d_in[5];
    const float* pw_W    = (const float*)d_in[6];
    const float* pw_b    = (const float*)d_in[7];
    const float* proj_W  = (const float*)d_in[8];
    const float* proj_b  = (const float*)d_in[9];

    float* pooled = (float*)d_ws;
    int*   R      = (int*)((char*)d_ws + (size_t)BB*WIDTH*sizeof(float));

    fno_pooled_kernel<<<BB, 256, 0, stream>>>(n, lift_W, lift_b, spec_Wr, spec_Wi,
                                              pw_W, pw_b, pooled, R);
    build_lu_kernel<<<BB, 512, 0, stream>>>(M_base, proj_W, proj_b, pooled, R,
                                            (float*)d_out);
}

// Round 4
// 519.961 us; speedup vs baseline: 1.3549x; 1.0718x over previous
//
#include <hip/hip_runtime.h>
#include <math.h>

#ifndef M_PI
#define M_PI 3.14159265358979323846
#endif

#define BB 1024
#define SIZE 512
#define NF 128
#define WIDTH 32
#define TOTAL (SIZE*NF)

// ---------------------------------------------------------------------------
// Swizzled LDS matrix layout: element (i,j) lives at float-index
//   i*128 + ((((j>>2) ^ (i&7)) << 2) | (j&3))
// ---------------------------------------------------------------------------
__device__ __forceinline__ int agrp(int i, int G) {
    return i*128 + ((G ^ (i & 7)) << 2);
}
__device__ __forceinline__ int aidx(int i, int j) {
    return i*128 + ((((j >> 2) ^ (i & 7)) << 2) | (j & 3));
}

// ---------------------------------------------------------------------------
// Kernel 1: per-sample FNO frontend -> pooled[b][32] and R[b][128]
// ---------------------------------------------------------------------------
__global__ __launch_bounds__(256) void fno_pooled_kernel(
    const int*   __restrict__ n,
    const float* __restrict__ lift_W,
    const float* __restrict__ lift_b,
    const float* __restrict__ spec_Wr,
    const float* __restrict__ spec_Wi,
    const float* __restrict__ pw_W,
    const float* __restrict__ pw_b,
    float* __restrict__ pooled_g,
    int*   __restrict__ R_g)
{
    __shared__ float nf[SIZE];
    __shared__ float c32[32], s32[32];
    __shared__ float Gre[16], Gim[16];
    __shared__ float wsum[4][32];
    __shared__ float Ar[WIDTH][16], Ai[WIDTH][16];
    __shared__ float lowr[WIDTH][16], lowi[WIDTH][16];
    __shared__ float pwl[WIDTH], cb0[WIDTH];
    __shared__ float Br[WIDTH], Bi[WIDTH];
    __shared__ int   Rl[NF];

    const int b = blockIdx.x;
    const int t = threadIdx.x;
    const int lane = t & 63;
    const int wave = t >> 6;

    if (t < 32) {
        float ang = (float)t * (2.0f * (float)M_PI / 32.0f);
        c32[t] = cosf(ang);
        s32[t] = sinf(ang);
    }
    for (int p = t; p < SIZE; p += 256) nf[p] = (float)n[b*SIZE + p];
    if (t < NF) Rl[t] = 0;
    __syncthreads();

    if (wave == 0) {
        int base = 0;
        for (int c = 0; c < 8; ++c) {
            int p = c*64 + lane;
            bool occ = (nf[p] != 0.0f);
            unsigned long long mask = __ballot(occ);
            int prefix = __popcll(mask & ((1ull << lane) - 1ull));
            if (occ) {
                int idx = base + prefix;
                if (idx < NF) Rl[idx] = p;
            }
            base += __popcll(mask);
        }
    }

    float gre[16], gim[16];
    #pragma unroll
    for (int m = 0; m < 16; ++m) { gre[m] = 0.f; gim[m] = 0.f; }
    for (int p = t; p < SIZE; p += 256) {
        float v = nf[p];
        int x = p >> 4, y = p & 15;
        #pragma unroll
        for (int kx = 0; kx < 4; ++kx) {
            #pragma unroll
            for (int ky = 0; ky < 4; ++ky) {
                int idx = (kx*x + 2*ky*y) & 31;
                gre[kx*4+ky] += v * c32[idx];
                gim[kx*4+ky] -= v * s32[idx];
            }
        }
    }
    #pragma unroll
    for (int m = 0; m < 16; ++m) {
        for (int off = 32; off > 0; off >>= 1) {
            gre[m] += __shfl_xor(gre[m], off, 64);
            gim[m] += __shfl_xor(gim[m], off, 64);
        }
    }
    if (lane == 0) {
        #pragma unroll
        for (int m = 0; m < 16; ++m) { wsum[wave][m] = gre[m]; wsum[wave][16+m] = gim[m]; }
    }
    __syncthreads();
    if (t < 32) {
        float s = wsum[0][t] + wsum[1][t] + wsum[2][t] + wsum[3][t];
        if (t < 16) Gre[t] = s; else Gim[t-16] = s;
    }

    for (int idx = t; idx < 512; idx += 256) {
        int o = idx >> 4, m = idx & 15;
        float ar = 0.f, ai = 0.f;
        for (int i = 0; i < WIDTH; ++i) {
            float lw = lift_W[i];
            ar += lw * spec_Wr[i*512 + o*16 + m];
            ai += lw * spec_Wi[i*512 + o*16 + m];
        }
        Ar[o][m] = ar; Ai[o][m] = ai;
    }
    if (t < 32) {
        float br = 0.f, bi = 0.f, pl = 0.f, cb = 0.f;
        for (int i = 0; i < WIDTH; ++i) {
            float lb = lift_b[i];
            br += lb * spec_Wr[i*512 + t*16 + 0];
            bi += lb * spec_Wi[i*512 + t*16 + 0];
            pl += lift_W[i] * pw_W[i*WIDTH + t];
            cb += lb * pw_W[i*WIDTH + t];
        }
        Br[t] = br; Bi[t] = bi;
        pwl[t] = pl;
        cb0[t] = cb + pw_b[t];
    }
    __syncthreads();

    for (int idx = t; idx < 512; idx += 256) {
        int o = idx >> 4, m = idx & 15;
        float gr = Gre[m], gi = Gim[m];
        float ar = Ar[o][m], ai = Ai[o][m];
        float lr = gr*ar - gi*ai;
        float li = gr*ai + gi*ar;
        if (m == 0) { lr += 512.f * Br[o]; li += 512.f * Bi[o]; }
        lowr[o][m] = lr; lowi[o][m] = li;
    }
    __syncthreads();

    const int o  = t >> 3;
    const int xg = t & 7;
    const float plo = pwl[o], cbo = cb0[o];
    float acc = 0.f;
    const float inv32 = 1.0f/32.0f, inv16 = 1.0f/16.0f;
    for (int xi = 0; xi < 4; ++xi) {
        int x = xg*4 + xi;
        float Tre[4], Tim[4];
        #pragma unroll
        for (int ky = 0; ky < 4; ++ky) { Tre[ky] = 0.f; Tim[ky] = 0.f; }
        #pragma unroll
        for (int kx = 0; kx < 4; ++kx) {
            int idx = (kx*x) & 31;
            float c = c32[idx], s = s32[idx];
            #pragma unroll
            for (int ky = 0; ky < 4; ++ky) {
                float lr = lowr[o][kx*4+ky], li = lowi[o][kx*4+ky];
                Tre[ky] += lr*c - li*s;
                Tim[ky] += lr*s + li*c;
            }
        }
        #pragma unroll
        for (int ky = 0; ky < 4; ++ky) { Tre[ky] *= inv32; Tim[ky] *= inv32; }
        for (int y = 0; y < 16; ++y) {
            float hsv = Tre[0];
            #pragma unroll
            for (int ky = 1; ky < 4; ++ky) {
                int idx = (2*ky*y) & 31;
                hsv += 2.f*(Tre[ky]*c32[idx] - Tim[ky]*s32[idx]);
            }
            hsv *= inv16;
            float z = hsv + nf[x*16 + y]*plo + cbo;
            acc += tanhf(z);
        }
    }
    acc += __shfl_down(acc, 4, 8);
    acc += __shfl_down(acc, 2, 8);
    acc += __shfl_down(acc, 1, 8);
    if ((t & 7) == 0) pooled_g[b*WIDTH + o] = acc * (1.0f/512.0f);

    if (t < NF) R_g[b*NF + t] = Rl[t];
}

// ---------------------------------------------------------------------------
// Kernel 2: build gathered A + rank-4 blocked LU (partial pivoting) -> out
// Pivot phase is fully register-resident in wave 0 (panel columns preloaded,
// U entries via shfl from the pivot lane, L11^{-1} in closed form).
// ---------------------------------------------------------------------------
__global__ __launch_bounds__(512, 4) void build_lu_kernel(
    const float* __restrict__ M_base,
    const float* __restrict__ proj_W,
    const float* __restrict__ proj_b,
    const float* __restrict__ pooled_g,
    const int*   __restrict__ R_g,
    float* __restrict__ out)
{
    __shared__ float A[128*128];       // swizzled
    __shared__ float Raw[4*128];       // pre-panel pivot rows, linear
    __shared__ float coefb[128*5];     // stride-5 pad
    __shared__ float Mb[16];
    __shared__ float pvbuf[128];
    __shared__ int   pivseq[128];
    __shared__ int   pr4[4];
    __shared__ float pooled_s[WIDTH];
    __shared__ int   Rl[NF];

    const int b = blockIdx.x;
    const int t = threadIdx.x;
    const int i = t & 127;
    const int q = t >> 7;

    if (t < WIDTH) pooled_s[t] = pooled_g[b*WIDTH + t];
    if (t < NF)    Rl[t] = R_g[b*NF + t];
    __syncthreads();

    // ---- build ----
    {
        const int r = Rl[i];
        const size_t off0 = (size_t)r*NF + q*32;
        float4 acc[8];
        const float4* mb = (const float4*)(M_base + off0);
        const float4* pb = (const float4*)(proj_b + off0);
        #pragma unroll
        for (int g = 0; g < 8; ++g) {
            float4 a = mb[g], c = pb[g];
            acc[g] = make_float4(a.x+c.x, a.y+c.y, a.z+c.z, a.w+c.w);
        }
        for (int o = 0; o < WIDTH; ++o) {
            const float p = pooled_s[o];
            const float4* w = (const float4*)(proj_W + (size_t)o*TOTAL + off0);
            #pragma unroll
            for (int g = 0; g < 8; ++g) {
                float4 wv = w[g];
                acc[g].x += p*wv.x; acc[g].y += p*wv.y;
                acc[g].z += p*wv.z; acc[g].w += p*wv.w;
            }
        }
        #pragma unroll
        for (int g = 0; g < 8; ++g)
            *((float4*)&A[agrp(i, q*8+g)]) = acc[g];
    }
    __syncthreads();

    bool done_i = false;
    bool done0 = false, done1 = false;

    for (int p = 0; p < 32; ++p) {
        const int c = 4*p;

        if (t < 64) {
            const int lane = t;
            float v0[4], v1[4];
            #pragma unroll
            for (int j = 0; j < 4; ++j) {
                v0[j] = A[aidx(lane,      c + j)];
                v1[j] = A[aidx(lane + 64, c + j)];
            }
            float lr0[4], lr1[4];
            int   prreg[4];

            #pragma unroll
            for (int k = 0; k < 4; ++k) {
                float cand0 = done0 ? -1.f : fabsf(v0[k]);
                float cand1 = done1 ? -1.f : fabsf(v1[k]);
                float ab, val; int idx;
                if (cand1 > cand0) { ab = cand1; val = v1[k]; idx = lane + 64; }
                else               { ab = cand0; val = v0[k]; idx = lane; }
                #pragma unroll
                for (int off = 32; off > 0; off >>= 1) {
                    float oab  = __shfl_xor(ab,  off, 64);
                    float oval = __shfl_xor(val, off, 64);
                    int   oidx = __shfl_xor(idx, off, 64);
                    if (oab > ab || (oab == ab && oidx < idx)) { ab = oab; val = oval; idx = oidx; }
                }
                const int   pk = idx;
                const float pv = val;
                prreg[k] = pk;
                if (lane == 0) { pivseq[c+k] = pk; pvbuf[c+k] = pv; }
                const float inv = 1.0f / pv;
                float l0 = (done0 || lane == pk)      ? 0.f : v0[k] * inv;
                float l1 = (done1 || lane + 64 == pk) ? 0.f : v1[k] * inv;
                lr0[k] = l0; lr1[k] = l1;
                if (lane == pk)      done0 = true;
                if (lane + 64 == pk) done1 = true;
                #pragma unroll
                for (int j = 0; j < 4; ++j) if (j > k) {
                    float src = (pk < 64) ? v0[j] : v1[j];
                    float ukj = __shfl(src, pk & 63, 64);
                    v0[j] -= l0 * ukj;
                    v1[j] -= l1 * ukj;
                }
            }

            // L11 strict-lower entries via shfl from pivot lanes
            float Lt10 = __shfl((prreg[1] < 64) ? lr0[0] : lr1[0], prreg[1] & 63, 64);
            float Lt20 = __shfl((prreg[2] < 64) ? lr0[0] : lr1[0], prreg[2] & 63, 64);
            float Lt21 = __shfl((prreg[2] < 64) ? lr0[1] : lr1[1], prreg[2] & 63, 64);
            float Lt30 = __shfl((prreg[3] < 64) ? lr0[0] : lr1[0], prreg[3] & 63, 64);
            float Lt31 = __shfl((prreg[3] < 64) ? lr0[1] : lr1[1], prreg[3] & 63, 64);
            float Lt32 = __shfl((prreg[3] < 64) ? lr0[2] : lr1[2], prreg[3] & 63, 64);

            // M = (I+Lt)^{-1} closed form (unit lower)
            const float m10 = -Lt10;
            const float m21 = -Lt21;
            const float m32 = -Lt32;
            const float m20 = -Lt20 + Lt21*Lt10;
            const float m31 = -Lt31 + Lt32*Lt21;
            const float m30 = -Lt30 + Lt31*Lt10 + Lt32*Lt20 - Lt32*Lt21*Lt10;

            if (lane < 4) pr4[lane] = prreg[lane];
            if (lane == 0) {
                Mb[0]=1.f;  Mb[1]=0.f;  Mb[2]=0.f;  Mb[3]=0.f;
                Mb[4]=m10;  Mb[5]=1.f;  Mb[6]=0.f;  Mb[7]=0.f;
                Mb[8]=m20;  Mb[9]=m21;  Mb[10]=1.f; Mb[11]=0.f;
                Mb[12]=m30; Mb[13]=m31; Mb[14]=m32; Mb[15]=1.f;
            }

            // composite coefs: coef = -(lrow . M), column form with unit diag
            {
                float c0 = -(lr0[0] + lr0[1]*m10 + lr0[2]*m20 + lr0[3]*m30);
                float c1 = -(lr0[1] + lr0[2]*m21 + lr0[3]*m31);
                float c2 = -(lr0[2] + lr0[3]*m32);
                float c3 = -(lr0[3]);
                coefb[lane*5 + 0] = c0; coefb[lane*5 + 1] = c1;
                coefb[lane*5 + 2] = c2; coefb[lane*5 + 3] = c3;
                float d0 = -(lr1[0] + lr1[1]*m10 + lr1[2]*m20 + lr1[3]*m30);
                float d1 = -(lr1[1] + lr1[2]*m21 + lr1[3]*m31);
                float d2 = -(lr1[2] + lr1[3]*m32);
                float d3 = -(lr1[3]);
                coefb[(lane+64)*5 + 0] = d0; coefb[(lane+64)*5 + 1] = d1;
                coefb[(lane+64)*5 + 2] = d2; coefb[(lane+64)*5 + 3] = d3;
            }

            // copy pivot rows (pre-panel values) to Raw (linear)
            #pragma unroll
            for (int h = 0; h < 2; ++h) {
                int id = lane + 64*h;
                int s = id >> 5, G = id & 31;
                *((float4*)&Raw[s*128 + G*4]) = *((const float4*)&A[agrp(prreg[s], G)]);
            }
        }
        __syncthreads();

        // rank-4 trailing update, stride-4 group ownership for load balance
        {
            int fp = -1;
            #pragma unroll
            for (int s = 0; s < 4; ++s) if (i == pr4[s]) fp = s;
            if (fp >= 0 || !done_i) {
                float cf[4];
                if (fp >= 0) {
                    #pragma unroll
                    for (int s = 0; s < 4; ++s) cf[s] = Mb[fp*4 + s];
                } else {
                    #pragma unroll
                    for (int s = 0; s < 4; ++s) cf[s] = coefb[i*5 + s];
                }
                #pragma unroll
                for (int g = 0; g < 8; ++g) {
                    const int G = q + 4*g;
                    if (G > p) {
                        float4 own;
                        if (fp >= 0) own = make_float4(0.f, 0.f, 0.f, 0.f);
                        else         own = *((const float4*)&A[agrp(i, G)]);
                        #pragma unroll
                        for (int s = 0; s < 4; ++s) {
                            float4 rv = *((const float4*)&Raw[s*128 + G*4]);
                            own.x += cf[s]*rv.x; own.y += cf[s]*rv.y;
                            own.z += cf[s]*rv.z; own.w += cf[s]*rv.w;
                        }
                        *((float4*)&A[agrp(i, G)]) = own;
                    }
                }
                if (fp >= 0) done_i = true;
            }
        }
        __syncthreads();
    }

    // ---- logabs + sign ----
    if (t < 64) {
        const int lane = t;
        float d0 = pvbuf[lane], d1 = pvbuf[lane + 64];
        float ls = logf(fabsf(d0)) + logf(fabsf(d1));
        int neg = ((d0 < 0.f) ? 1 : 0) ^ ((d1 < 0.f) ? 1 : 0);
        #pragma unroll
        for (int off = 32; off > 0; off >>= 1) {
            ls  += __shfl_xor(ls,  off, 64);
            neg ^= __shfl_xor(neg, off, 64);
        }
        if (lane == 0) {
            unsigned long long vis0 = 0ull, vis1 = 0ull;
            int trans = 0;
            for (int k = 0; k < 128; ++k) {
                bool vk = (k < 64) ? ((vis0 >> k) & 1ull) : ((vis1 >> (k - 64)) & 1ull);
                if (!vk) {
                    int j = k, len = 0;
                    while (true) {
                        bool vj = (j < 64) ? ((vis0 >> j) & 1ull) : ((vis1 >> (j - 64)) & 1ull);
                        if (vj) break;
                        if (j < 64) vis0 |= (1ull << j); else vis1 |= (1ull << (j - 64));
                        j = pivseq[j];
                        ++len;
                    }
                    trans += len - 1;
                }
            }
            int parity = (neg ^ (trans & 1)) & 1;
            out[b]      = ls;
            out[BB + b] = parity ? (float)M_PI : 0.0f;
        }
    }
}

// ---------------------------------------------------------------------------
extern "C" void kernel_launch(void* const* d_in, const int* in_sizes, int n_in,
                              void* d_out, int out_size, void* d_ws, size_t ws_size,
                              hipStream_t stream) {
    const int*   n       = (const int*)  d_in[0];
    const float* M_base  = (const float*)d_in[1];
    const float* lift_W  = (const float*)d_in[2];
    const float* lift_b  = (const float*)d_in[3];
    const float* spec_Wr = (const float*)d_in[4];
    const float* spec_Wi = (const float*)d_in[5];
    const float* pw_W    = (const float*)d_in[6];
    const float* pw_b    = (const float*)d_in[7];
    const float* proj_W  = (const float*)d_in[8];
    const float* proj_b  = (const float*)d_in[9];

    float* pooled = (float*)d_ws;
    int*   R      = (int*)((char*)d_ws + (size_t)BB*WIDTH*sizeof(float));

    fno_pooled_kernel<<<BB, 256, 0, stream>>>(n, lift_W, lift_b, spec_Wr, spec_Wi,
                                              pw_W, pw_b, pooled, R);
    build_lu_kernel<<<BB, 512, 0, stream>>>(M_base, proj_W, proj_b, pooled, R,
                                            (float*)d_out);
}

// Round 5
// 424.953 us; speedup vs baseline: 1.6578x; 1.2236x over previous
//
#include <hip/hip_runtime.h>
#include <math.h>

#ifndef M_PI
#define M_PI 3.14159265358979323846
#endif

#define BB 1024
#define SIZE 512
#define NF 128
#define WIDTH 32
#define TOTAL (SIZE*NF)

// ---------------------------------------------------------------------------
// Swizzled LDS matrix layout: element (i,j) lives at float-index
//   i*128 + ((((j>>2) ^ (i&7)) << 2) | (j&3))
// Groups of 4 floats contiguous (b128-able); group index XOR'd with i&7 so
// a fixed-group column access is conflict-free across 8-lane packets.
// ---------------------------------------------------------------------------
__device__ __forceinline__ int agrp(int i, int G) {
    return i*128 + ((G ^ (i & 7)) << 2);
}

// DPP-based unsigned max reduce step (VALU latency, no LDS pipe)
#define DPP_UMAX(x, ctrl, rmask) { \
    unsigned _t = (unsigned)__builtin_amdgcn_update_dpp(0, (int)(x), (ctrl), (rmask), 0xf, false); \
    if (_t > (x)) (x) = _t; }

__device__ __forceinline__ float readlanef(float x, int l) {
    return __int_as_float(__builtin_amdgcn_readlane(__float_as_int(x), l));
}

// ---------------------------------------------------------------------------
// Kernel 1: per-sample FNO frontend -> pooled[b][32] and R[b][128]
// ---------------------------------------------------------------------------
__global__ __launch_bounds__(256) void fno_pooled_kernel(
    const int*   __restrict__ n,
    const float* __restrict__ lift_W,
    const float* __restrict__ lift_b,
    const float* __restrict__ spec_Wr,
    const float* __restrict__ spec_Wi,
    const float* __restrict__ pw_W,
    const float* __restrict__ pw_b,
    float* __restrict__ pooled_g,
    int*   __restrict__ R_g)
{
    __shared__ float nf[SIZE];
    __shared__ float c32[32], s32[32];
    __shared__ float Gre[16], Gim[16];
    __shared__ float wsum[4][32];
    __shared__ float Ar[WIDTH][16], Ai[WIDTH][16];
    __shared__ float lowr[WIDTH][16], lowi[WIDTH][16];
    __shared__ float pwl[WIDTH], cb0[WIDTH];
    __shared__ float Br[WIDTH], Bi[WIDTH];
    __shared__ int   Rl[NF];

    const int b = blockIdx.x;
    const int t = threadIdx.x;
    const int lane = t & 63;
    const int wave = t >> 6;

    if (t < 32) {
        float ang = (float)t * (2.0f * (float)M_PI / 32.0f);
        c32[t] = cosf(ang);
        s32[t] = sinf(ang);
    }
    for (int p = t; p < SIZE; p += 256) nf[p] = (float)n[b*SIZE + p];
    if (t < NF) Rl[t] = 0;
    __syncthreads();

    if (wave == 0) {
        int base = 0;
        for (int c = 0; c < 8; ++c) {
            int p = c*64 + lane;
            bool occ = (nf[p] != 0.0f);
            unsigned long long mask = __ballot(occ);
            int prefix = __popcll(mask & ((1ull << lane) - 1ull));
            if (occ) {
                int idx = base + prefix;
                if (idx < NF) Rl[idx] = p;
            }
            base += __popcll(mask);
        }
    }

    float gre[16], gim[16];
    #pragma unroll
    for (int m = 0; m < 16; ++m) { gre[m] = 0.f; gim[m] = 0.f; }
    for (int p = t; p < SIZE; p += 256) {
        float v = nf[p];
        int x = p >> 4, y = p & 15;
        #pragma unroll
        for (int kx = 0; kx < 4; ++kx) {
            #pragma unroll
            for (int ky = 0; ky < 4; ++ky) {
                int idx = (kx*x + 2*ky*y) & 31;
                gre[kx*4+ky] += v * c32[idx];
                gim[kx*4+ky] -= v * s32[idx];
            }
        }
    }
    #pragma unroll
    for (int m = 0; m < 16; ++m) {
        for (int off = 32; off > 0; off >>= 1) {
            gre[m] += __shfl_xor(gre[m], off, 64);
            gim[m] += __shfl_xor(gim[m], off, 64);
        }
    }
    if (lane == 0) {
        #pragma unroll
        for (int m = 0; m < 16; ++m) { wsum[wave][m] = gre[m]; wsum[wave][16+m] = gim[m]; }
    }
    __syncthreads();
    if (t < 32) {
        float s = wsum[0][t] + wsum[1][t] + wsum[2][t] + wsum[3][t];
        if (t < 16) Gre[t] = s; else Gim[t-16] = s;
    }

    for (int idx = t; idx < 512; idx += 256) {
        int o = idx >> 4, m = idx & 15;
        float ar = 0.f, ai = 0.f;
        for (int i = 0; i < WIDTH; ++i) {
            float lw = lift_W[i];
            ar += lw * spec_Wr[i*512 + o*16 + m];
            ai += lw * spec_Wi[i*512 + o*16 + m];
        }
        Ar[o][m] = ar; Ai[o][m] = ai;
    }
    if (t < 32) {
        float br = 0.f, bi = 0.f, pl = 0.f, cb = 0.f;
        for (int i = 0; i < WIDTH; ++i) {
            float lb = lift_b[i];
            br += lb * spec_Wr[i*512 + t*16 + 0];
            bi += lb * spec_Wi[i*512 + t*16 + 0];
            pl += lift_W[i] * pw_W[i*WIDTH + t];
            cb += lb * pw_W[i*WIDTH + t];
        }
        Br[t] = br; Bi[t] = bi;
        pwl[t] = pl;
        cb0[t] = cb + pw_b[t];
    }
    __syncthreads();

    for (int idx = t; idx < 512; idx += 256) {
        int o = idx >> 4, m = idx & 15;
        float gr = Gre[m], gi = Gim[m];
        float ar = Ar[o][m], ai = Ai[o][m];
        float lr = gr*ar - gi*ai;
        float li = gr*ai + gi*ar;
        if (m == 0) { lr += 512.f * Br[o]; li += 512.f * Bi[o]; }
        lowr[o][m] = lr; lowi[o][m] = li;
    }
    __syncthreads();

    const int o  = t >> 3;
    const int xg = t & 7;
    const float plo = pwl[o], cbo = cb0[o];
    float acc = 0.f;
    const float inv32 = 1.0f/32.0f, inv16 = 1.0f/16.0f;
    for (int xi = 0; xi < 4; ++xi) {
        int x = xg*4 + xi;
        float Tre[4], Tim[4];
        #pragma unroll
        for (int ky = 0; ky < 4; ++ky) { Tre[ky] = 0.f; Tim[ky] = 0.f; }
        #pragma unroll
        for (int kx = 0; kx < 4; ++kx) {
            int idx = (kx*x) & 31;
            float c = c32[idx], s = s32[idx];
            #pragma unroll
            for (int ky = 0; ky < 4; ++ky) {
                float lr = lowr[o][kx*4+ky], li = lowi[o][kx*4+ky];
                Tre[ky] += lr*c - li*s;
                Tim[ky] += lr*s + li*c;
            }
        }
        #pragma unroll
        for (int ky = 0; ky < 4; ++ky) { Tre[ky] *= inv32; Tim[ky] *= inv32; }
        for (int y = 0; y < 16; ++y) {
            float hsv = Tre[0];
            #pragma unroll
            for (int ky = 1; ky < 4; ++ky) {
                int idx = (2*ky*y) & 31;
                hsv += 2.f*(Tre[ky]*c32[idx] - Tim[ky]*s32[idx]);
            }
            hsv *= inv16;
            float z = hsv + nf[x*16 + y]*plo + cbo;
            acc += tanhf(z);
        }
    }
    acc += __shfl_down(acc, 4, 8);
    acc += __shfl_down(acc, 2, 8);
    acc += __shfl_down(acc, 1, 8);
    if ((t & 7) == 0) pooled_g[b*WIDTH + o] = acc * (1.0f/512.0f);

    if (t < NF) R_g[b*NF + t] = Rl[t];
}

// ---------------------------------------------------------------------------
// Kernel 2: build gathered A + rank-4 blocked LU (partial pivoting) -> out
// Pivot phase: DPP max-reduce on abs-bits + ballot/ffs winner + readlane
// broadcasts — no ds_bpermute on the critical chain.
// ---------------------------------------------------------------------------
__global__ __launch_bounds__(512, 4) void build_lu_kernel(
    const float* __restrict__ M_base,
    const float* __restrict__ proj_W,
    const float* __restrict__ proj_b,
    const float* __restrict__ pooled_g,
    const int*   __restrict__ R_g,
    float* __restrict__ out)
{
    __shared__ float A[128*128];       // swizzled
    __shared__ float Raw[4*128];       // pre-panel pivot rows, linear
    __shared__ float coefb[128*5];     // stride-5 pad
    __shared__ float Mb[16];
    __shared__ float pvbuf[128];
    __shared__ int   pivseq[128];
    __shared__ int   pr4[4];
    __shared__ float pooled_s[WIDTH];
    __shared__ int   Rl[NF];

    const int b = blockIdx.x;
    const int t = threadIdx.x;
    const int i = t & 127;
    const int q = t >> 7;

    if (t < WIDTH) pooled_s[t] = pooled_g[b*WIDTH + t];
    if (t < NF)    Rl[t] = R_g[b*NF + t];
    __syncthreads();

    // ---- build ----
    {
        const int r = Rl[i];
        const size_t off0 = (size_t)r*NF + q*32;
        float4 acc[8];
        const float4* mb = (const float4*)(M_base + off0);
        const float4* pb = (const float4*)(proj_b + off0);
        #pragma unroll
        for (int g = 0; g < 8; ++g) {
            float4 a = mb[g], c = pb[g];
            acc[g] = make_float4(a.x+c.x, a.y+c.y, a.z+c.z, a.w+c.w);
        }
        for (int o = 0; o < WIDTH; ++o) {
            const float p = pooled_s[o];
            const float4* w = (const float4*)(proj_W + (size_t)o*TOTAL + off0);
            #pragma unroll
            for (int g = 0; g < 8; ++g) {
                float4 wv = w[g];
                acc[g].x += p*wv.x; acc[g].y += p*wv.y;
                acc[g].z += p*wv.z; acc[g].w += p*wv.w;
            }
        }
        #pragma unroll
        for (int g = 0; g < 8; ++g)
            *((float4*)&A[agrp(i, q*8+g)]) = acc[g];
    }
    __syncthreads();

    bool done_i = false;
    bool done0 = false, done1 = false;

    for (int p = 0; p < 32; ++p) {
        const int c = 4*p;

        if (t < 64) {
            const int lane = t;
            // panel group p = columns c..c+3, one b128 per row-half
            float4 r0 = *((const float4*)&A[agrp(lane,      p)]);
            float4 r1 = *((const float4*)&A[agrp(lane + 64, p)]);
            float v0[4] = { r0.x, r0.y, r0.z, r0.w };
            float v1[4] = { r1.x, r1.y, r1.z, r1.w };
            float lr0[4], lr1[4];
            int   prreg[4];

            #pragma unroll
            for (int k = 0; k < 4; ++k) {
                unsigned k0 = done0 ? 0u : (__float_as_uint(v0[k]) & 0x7fffffffu);
                unsigned k1 = done1 ? 0u : (__float_as_uint(v1[k]) & 0x7fffffffu);
                unsigned key = (k0 > k1) ? k0 : k1;
                DPP_UMAX(key, 0x111, 0xf);   // row_shr:1
                DPP_UMAX(key, 0x112, 0xf);   // row_shr:2
                DPP_UMAX(key, 0x114, 0xf);   // row_shr:4
                DPP_UMAX(key, 0x118, 0xf);   // row_shr:8
                DPP_UMAX(key, 0x142, 0xa);   // row_bcast:15
                DPP_UMAX(key, 0x143, 0xc);   // row_bcast:31
                const unsigned best = (unsigned)__builtin_amdgcn_readlane((int)key, 63);
                const unsigned long long b0m = __ballot(k0 == best);
                const unsigned long long b1m = __ballot(k1 == best);
                int lw, row; float pv;
                if (b0m) {
                    lw = __ffsll((unsigned long long)b0m) - 1; row = lw;
                    pv = readlanef(v0[k], lw);
                } else {
                    lw = __ffsll((unsigned long long)b1m) - 1; row = lw + 64;
                    pv = readlanef(v1[k], lw);
                }
                prreg[k] = row;
                const float inv = 1.0f / pv;
                float l0 = (done0 || row == lane)      ? 0.f : v0[k] * inv;
                float l1 = (done1 || row == lane + 64) ? 0.f : v1[k] * inv;
                lr0[k] = l0; lr1[k] = l1;
                if (row == lane)      done0 = true;
                if (row == lane + 64) done1 = true;
                const bool lowhalf = (row < 64);
                #pragma unroll
                for (int j = 0; j < 4; ++j) if (j > k) {
                    float ukj = lowhalf ? readlanef(v0[j], lw) : readlanef(v1[j], lw);
                    v0[j] -= l0 * ukj;
                    v1[j] -= l1 * ukj;
                }
                if (lane == 0) { pivseq[c+k] = row; pvbuf[c+k] = pv; }
            }

            // L11 strict-lower entries via readlane (all uniform)
            const int pa = prreg[1], pb_ = prreg[2], pc = prreg[3];
            const float Lt10 = (pa  < 64) ? readlanef(lr0[0], pa)      : readlanef(lr1[0], pa - 64);
            const float Lt20 = (pb_ < 64) ? readlanef(lr0[0], pb_)     : readlanef(lr1[0], pb_ - 64);
            const float Lt21 = (pb_ < 64) ? readlanef(lr0[1], pb_)     : readlanef(lr1[1], pb_ - 64);
            const float Lt30 = (pc  < 64) ? readlanef(lr0[0], pc)      : readlanef(lr1[0], pc - 64);
            const float Lt31 = (pc  < 64) ? readlanef(lr0[1], pc)      : readlanef(lr1[1], pc - 64);
            const float Lt32 = (pc  < 64) ? readlanef(lr0[2], pc)      : readlanef(lr1[2], pc - 64);

            // M = (I+Lt)^{-1} closed form (unit lower)
            const float m10 = -Lt10;
            const float m21 = -Lt21;
            const float m32 = -Lt32;
            const float m20 = -Lt20 + Lt21*Lt10;
            const float m31 = -Lt31 + Lt32*Lt21;
            const float m30 = -Lt30 + Lt31*Lt10 + Lt32*Lt20 - Lt32*Lt21*Lt10;

            if (lane == 0) {
                pr4[0] = prreg[0]; pr4[1] = prreg[1];
                pr4[2] = prreg[2]; pr4[3] = prreg[3];
                Mb[0]=1.f;  Mb[1]=0.f;  Mb[2]=0.f;  Mb[3]=0.f;
                Mb[4]=m10;  Mb[5]=1.f;  Mb[6]=0.f;  Mb[7]=0.f;
                Mb[8]=m20;  Mb[9]=m21;  Mb[10]=1.f; Mb[11]=0.f;
                Mb[12]=m30; Mb[13]=m31; Mb[14]=m32; Mb[15]=1.f;
            }

            // composite coefs: coef = -(lrow . M)
            {
                float c0 = -(lr0[0] + lr0[1]*m10 + lr0[2]*m20 + lr0[3]*m30);
                float c1 = -(lr0[1] + lr0[2]*m21 + lr0[3]*m31);
                float c2 = -(lr0[2] + lr0[3]*m32);
                float c3 = -(lr0[3]);
                coefb[lane*5 + 0] = c0; coefb[lane*5 + 1] = c1;
                coefb[lane*5 + 2] = c2; coefb[lane*5 + 3] = c3;
                float d0 = -(lr1[0] + lr1[1]*m10 + lr1[2]*m20 + lr1[3]*m30);
                float d1 = -(lr1[1] + lr1[2]*m21 + lr1[3]*m31);
                float d2 = -(lr1[2] + lr1[3]*m32);
                float d3 = -(lr1[3]);
                coefb[(lane+64)*5 + 0] = d0; coefb[(lane+64)*5 + 1] = d1;
                coefb[(lane+64)*5 + 2] = d2; coefb[(lane+64)*5 + 3] = d3;
            }

            // copy pivot rows (pre-panel values) to Raw (linear)
            #pragma unroll
            for (int h = 0; h < 2; ++h) {
                int id = lane + 64*h;
                int s = id >> 5, G = id & 31;
                *((float4*)&Raw[s*128 + G*4]) = *((const float4*)&A[agrp(prreg[s], G)]);
            }
        }
        __syncthreads();

        // rank-4 trailing update, stride-4 group ownership
        {
            int fp = -1;
            #pragma unroll
            for (int s = 0; s < 4; ++s) if (i == pr4[s]) fp = s;
            if (fp >= 0 || !done_i) {
                float cf[4];
                if (fp >= 0) {
                    #pragma unroll
                    for (int s = 0; s < 4; ++s) cf[s] = Mb[fp*4 + s];
                } else {
                    #pragma unroll
                    for (int s = 0; s < 4; ++s) cf[s] = coefb[i*5 + s];
                }
                #pragma unroll
                for (int g = 0; g < 8; ++g) {
                    const int G = q + 4*g;
                    if (G > p) {
                        float4 own;
                        if (fp >= 0) own = make_float4(0.f, 0.f, 0.f, 0.f);
                        else         own = *((const float4*)&A[agrp(i, G)]);
                        #pragma unroll
                        for (int s = 0; s < 4; ++s) {
                            float4 rv = *((const float4*)&Raw[s*128 + G*4]);
                            own.x += cf[s]*rv.x; own.y += cf[s]*rv.y;
                            own.z += cf[s]*rv.z; own.w += cf[s]*rv.w;
                        }
                        *((float4*)&A[agrp(i, G)]) = own;
                    }
                }
                if (fp >= 0) done_i = true;
            }
        }
        __syncthreads();
    }

    // ---- logabs + sign ----
    if (t < 64) {
        const int lane = t;
        float d0 = pvbuf[lane], d1 = pvbuf[lane + 64];
        float ls = logf(fabsf(d0)) + logf(fabsf(d1));
        int neg = ((d0 < 0.f) ? 1 : 0) ^ ((d1 < 0.f) ? 1 : 0);
        #pragma unroll
        for (int off = 32; off > 0; off >>= 1) {
            ls  += __shfl_xor(ls,  off, 64);
            neg ^= __shfl_xor(neg, off, 64);
        }
        if (lane == 0) {
            unsigned long long vis0 = 0ull, vis1 = 0ull;
            int trans = 0;
            for (int k = 0; k < 128; ++k) {
                bool vk = (k < 64) ? ((vis0 >> k) & 1ull) : ((vis1 >> (k - 64)) & 1ull);
                if (!vk) {
                    int j = k, len = 0;
                    while (true) {
                        bool vj = (j < 64) ? ((vis0 >> j) & 1ull) : ((vis1 >> (j - 64)) & 1ull);
                        if (vj) break;
                        if (j < 64) vis0 |= (1ull << j); else vis1 |= (1ull << (j - 64));
                        j = pivseq[j];
                        ++len;
                    }
                    trans += len - 1;
                }
            }
            int parity = (neg ^ (trans & 1)) & 1;
            out[b]      = ls;
            out[BB + b] = parity ? (float)M_PI : 0.0f;
        }
    }
}

// ---------------------------------------------------------------------------
extern "C" void kernel_launch(void* const* d_in, const int* in_sizes, int n_in,
                              void* d_out, int out_size, void* d_ws, size_t ws_size,
                              hipStream_t stream) {
    const int*   n       = (const int*)  d_in[0];
    const float* M_base  = (const float*)d_in[1];
    const float* lift_W  = (const float*)d_in[2];
    const float* lift_b  = (const float*)d_in[3];
    const float* spec_Wr = (const float*)d_in[4];
    const float* spec_Wi = (const float*)d_in[5];
    const float* pw_W    = (const float*)d_in[6];
    const float* pw_b    = (const float*)d_in[7];
    const float* proj_W  = (const float*)d_in[8];
    const float* proj_b  = (const float*)d_in[9];

    float* pooled = (float*)d_ws;
    int*   R      = (int*)((char*)d_ws + (size_t)BB*WIDTH*sizeof(float));

    fno_pooled_kernel<<<BB, 256, 0, stream>>>(n, lift_W, lift_b, spec_Wr, spec_Wi,
                                              pw_W, pw_b, pooled, R);
    build_lu_kernel<<<BB, 512, 0, stream>>>(M_base, proj_W, proj_b, pooled, R,
                                            (float*)d_out);
}